// Round 1
// baseline (792.147 us; speedup 1.0000x reference)
//
#include <hip/hip_runtime.h>

#define C 128
#define IN_A 1024
#define IN_V 512
#define NNODE 20000
#define NE 120000
#define NA 10000
#define NV 10000
#define EPSBN 1e-5f

#define NPAD 20032   // 64-aligned >= NNODE
#define EPAD 120064  // 64-aligned >= NE
#define APAD 10048   // 64-aligned >= NA/NV

typedef __bf16 bf16_t;
typedef bf16_t bf16x8 __attribute__((ext_vector_type(8)));
typedef float f32x4 __attribute__((ext_vector_type(4)));
typedef unsigned int u32;

__device__ __forceinline__ u32 encf(float f) {
    u32 u = __float_as_uint(f);
    return (u & 0x80000000u) ? ~u : (u | 0x80000000u);
}
__device__ __forceinline__ float decf(u32 u) {
    if (u == 0u) return 0.0f;
    u32 b = (u & 0x80000000u) ? (u & 0x7fffffffu) : ~u;
    return __uint_as_float(b);
}
__device__ __forceinline__ f32x4 ld4(const float* p) {
    return *reinterpret_cast<const f32x4*>(p);
}

struct GArgs {
    const void* A; long lda;          // ASRC0: bf16, ASRC1: f32
    const bf16_t* B; long ldb; int K;
    int M; const int* cnt;            // if cnt != null, M = *cnt (upper bound M for grid)
    const float* sA; const float* shA;   // ASRC1/2 bn scale/shift over K channels (null => raw cvt)
    const float* F;                       // ASRC2 node features f32 [N,C]
    const int* elist; const int* esrc; const int* edst;
    const float* sE; const float* shE;    // EPI1/2 bn scale/shift over out channels
    const float* bias;                    // EPI1
    const float* Ugat;                    // EPI2
    float* outF;                          // EPI0/1
    bf16_t* outH;                         // EPI2
    u32* agg;                             // EPI3
};

// ASRC: 0 = bf16 direct, 1 = f32 (+optional bn/relu), 2 = edge diff bn/relu
// EPI:  0 = store f32, 1 = bias+bn+relu store f32, 2 = +U[dst], bn+relu -> bf16, 3 = enc+atomicMax
template<int ASRC, int EPI>
__global__ __launch_bounds__(256) void gemm_kernel(GArgs g) {
    int Mreal = g.cnt ? *g.cnt : g.M;
    if (Mreal <= 0) return;
    int wave = threadIdx.x >> 6;
    int lane = threadIdx.x & 63;
    int m0 = blockIdx.x * 64 + wave * 16;
    if (m0 >= Mreal) return;

    int arow = m0 + (lane & 15);
    int ar = arow < Mreal ? arow : (Mreal - 1);   // clamp: stay in valid rows
    int ak = (lane >> 4) << 3;                    // k sub-offset 0/8/16/24

    const bf16_t* Bp = g.B + (size_t)(lane & 15) * g.ldb + ak;

    const bf16_t* Ab = nullptr;
    const float* Af = nullptr;
    const float* Fs = nullptr;
    const float* Fd = nullptr;
    if (ASRC == 0) Ab = (const bf16_t*)g.A + (size_t)ar * g.lda + ak;
    if (ASRC == 1) Af = (const float*)g.A + (size_t)ar * g.lda + ak;
    if (ASRC == 2) {
        int e = g.elist[ar];
        Fs = g.F + (size_t)g.esrc[e] * C + ak;
        Fd = g.F + (size_t)g.edst[e] * C + ak;
    }

    f32x4 acc[8];
#pragma unroll
    for (int i = 0; i < 8; i++) acc[i] = (f32x4)(0.0f);

    for (int kk = 0; kk < g.K; kk += 32) {
        bf16x8 a;
        if (ASRC == 0) {
            a = *reinterpret_cast<const bf16x8*>(Ab + kk);
        } else if (ASRC == 1) {
            f32x4 v0 = ld4(Af + kk), v1 = ld4(Af + kk + 4);
            if (g.sA) {
                f32x4 s0 = ld4(g.sA + kk + ak), s1 = ld4(g.sA + kk + ak + 4);
                f32x4 h0 = ld4(g.shA + kk + ak), h1 = ld4(g.shA + kk + ak + 4);
#pragma unroll
                for (int j = 0; j < 4; j++) {
                    v0[j] = fmaxf(v0[j] * s0[j] + h0[j], 0.0f);
                    v1[j] = fmaxf(v1[j] * s1[j] + h1[j], 0.0f);
                }
            }
#pragma unroll
            for (int j = 0; j < 4; j++) { a[j] = (bf16_t)v0[j]; a[4 + j] = (bf16_t)v1[j]; }
        } else {
            f32x4 vs0 = ld4(Fs + kk), vs1 = ld4(Fs + kk + 4);
            f32x4 vd0 = ld4(Fd + kk), vd1 = ld4(Fd + kk + 4);
            f32x4 s0 = ld4(g.sA + kk + ak), s1 = ld4(g.sA + kk + ak + 4);
            f32x4 h0 = ld4(g.shA + kk + ak), h1 = ld4(g.shA + kk + ak + 4);
#pragma unroll
            for (int j = 0; j < 4; j++) {
                float t0 = fmaxf((vs0[j] - vd0[j]) * s0[j] + h0[j], 0.0f);
                float t1 = fmaxf((vs1[j] - vd1[j]) * s1[j] + h1[j], 0.0f);
                a[j] = (bf16_t)t0; a[4 + j] = (bf16_t)t1;
            }
        }
#pragma unroll
        for (int nt = 0; nt < 8; nt++) {
            bf16x8 b = *reinterpret_cast<const bf16x8*>(Bp + (size_t)nt * 16 * g.ldb + kk);
            acc[nt] = __builtin_amdgcn_mfma_f32_16x16x32_bf16(a, b, acc[nt], 0, 0, 0);
        }
    }

    // epilogue: C/D layout col = lane&15, row = (lane>>4)*4 + j  [measured m89]
    int cb = lane & 15;
    float se[8], he[8], bsv[8];
    if (EPI == 1 || EPI == 2) {
#pragma unroll
        for (int nt = 0; nt < 8; nt++) { se[nt] = g.sE[nt * 16 + cb]; he[nt] = g.shE[nt * 16 + cb]; }
    }
    if (EPI == 1) {
#pragma unroll
        for (int nt = 0; nt < 8; nt++) bsv[nt] = g.bias[nt * 16 + cb];
    }
#pragma unroll
    for (int j = 0; j < 4; j++) {
        int m = m0 + (lane >> 4) * 4 + j;
        if (m >= Mreal) continue;
        int e = 0, d = 0;
        if (EPI >= 2) { e = g.elist[m]; d = g.edst[e]; }
#pragma unroll
        for (int nt = 0; nt < 8; nt++) {
            int n = nt * 16 + cb;
            float v = acc[nt][j];
            if (EPI == 0) {
                g.outF[(size_t)m * C + n] = v;
            } else if (EPI == 1) {
                g.outF[(size_t)m * C + n] = fmaxf((v + bsv[nt]) * se[nt] + he[nt], 0.0f);
            } else if (EPI == 2) {
                v += g.Ugat[(size_t)d * C + n];
                g.outH[(size_t)m * C + n] = (bf16_t)fmaxf(v * se[nt] + he[nt], 0.0f);
            } else {
                atomicMax(g.agg + (size_t)d * C + n, encf(v));
            }
        }
    }
}

__global__ void compact_kernel(const int* __restrict__ delta, const int* __restrict__ self,
                               int* __restrict__ list1, int* __restrict__ list2, int* __restrict__ cnts) {
    int e = blockIdx.x * 256 + threadIdx.x;
    if (e >= NE) return;
    int d = delta[e];
    bool a1 = (d < 1);
    bool a2 = ((d >= 1) && (d < 4)) || (self[e] == 1);
    if (a1) { int p = atomicAdd(&cnts[0], 1); list1[p] = e; }
    if (a2) { int p = atomicAdd(&cnts[1], 1); list2[p] = e; }
}

__global__ void cvt_weights(const float* __restrict__ w0a, const float* __restrict__ w0v,
                            const float* __restrict__ fc1, const float* __restrict__ fc2,
                            bf16_t* __restrict__ o) {
    const int TOT = 131072 + 65536 + 262144 + 131072; // 589824
    int i = blockIdx.x * 256 + threadIdx.x;
    int st = gridDim.x * 256;
    for (; i < TOT; i += st) {
        float v;
        if (i < 131072) v = w0a[i];
        else if (i < 196608) v = w0v[i - 131072];
        else if (i < 458752) v = fc1[i - 196608];
        else v = fc2[i - 458752];
        o[i] = (bf16_t)v;
    }
}

// SBN pairs of (scale[128], shift[128]): 0 = bn0; 1..3 = bn_node[0..2];
// 4..11 = bn1a[k]; 12..19 = bn1b[k]; 20..27 = bn2[k]
__global__ void prep_bn(const float* __restrict__ bn0, const float* __restrict__ bnn,
                        const float* __restrict__ ecb1, const float* __restrict__ ecb2,
                        float* __restrict__ SBN) {
    int i = blockIdx.x * 256 + threadIdx.x;
    if (i >= 28 * 128) return;
    int pair = i >> 7, c = i & 127;
    float gg, bb, mm, vv;
    if (pair == 0)      { gg = bn0[c]; bb = bn0[128 + c]; mm = bn0[256 + c]; vv = bn0[384 + c]; }
    else if (pair < 4)  { const float* q = bnn + (pair - 1) * 512;
                          gg = q[c]; bb = q[128 + c]; mm = q[256 + c]; vv = q[384 + c]; }
    else if (pair < 12) { const float* q = ecb1 + (pair - 4) * 1024;
                          gg = q[c]; bb = q[256 + c]; mm = q[512 + c]; vv = q[768 + c]; }
    else if (pair < 20) { const float* q = ecb1 + (pair - 12) * 1024 + 128;
                          gg = q[c]; bb = q[256 + c]; mm = q[512 + c]; vv = q[768 + c]; }
    else                { const float* q = ecb2 + (pair - 20) * 512;
                          gg = q[c]; bb = q[128 + c]; mm = q[256 + c]; vv = q[384 + c]; }
    float s = gg * rsqrtf(vv + EPSBN);
    SBN[pair * 256 + c] = s;
    SBN[pair * 256 + 128 + c] = bb - mm * s;
}

// mode: 0 plain decode; 1 bn+relu; 2 res+bn+relu; 3 res only. Also re-zeros agg.
__global__ void decode_kernel(u32* __restrict__ agg, const float* __restrict__ res,
                              const float* __restrict__ s, const float* __restrict__ sh,
                              float* __restrict__ out, int mode) {
    int idx = blockIdx.x * 256 + threadIdx.x;
    int stride = gridDim.x * 256;
    for (; idx < NNODE * C; idx += stride) {
        u32 u = agg[idx];
        agg[idx] = 0u;
        float v = decf(u);
        if (mode >= 2) v += res[idx];
        if (mode == 1 || mode == 2) {
            int c = idx & (C - 1);
            v = fmaxf(v * s[c] + sh[c], 0.0f);
        }
        out[idx] = v;
    }
}

// mode 0: final head (w_heads[0], out[0..]); mode 1: audio/video heads from g0
__global__ void head_kernel(const float* __restrict__ F, const float* __restrict__ wh,
                            const float* __restrict__ bh, float* __restrict__ out, int mode) {
    int node = blockIdx.x * 4 + (threadIdx.x >> 6);
    int lane = threadIdx.x & 63;
    if (node >= NNODE) return;
    int hsel = (mode == 0) ? 0 : ((node < NA) ? 1 : 2);
    const float* w = wh + hsel * 256;
    const float* f = F + (size_t)node * C;
    float f0 = f[lane], f1 = f[lane + 64];
    float p0 = f0 * w[lane] + f1 * w[lane + 64];
    float p1 = f0 * w[128 + lane] + f1 * w[192 + lane];
#pragma unroll
    for (int o = 32; o; o >>= 1) { p0 += __shfl_down(p0, o); p1 += __shfl_down(p1, o); }
    if (lane == 0) {
        float* op;
        if (mode == 0) op = out + (size_t)node * 2;
        else if (node < NA) op = out + 40000 + (size_t)node * 2;
        else op = out + 60000 + (size_t)(node - NA) * 2;
        op[0] = p0 + bh[hsel * 2 + 0];
        op[1] = p1 + bh[hsel * 2 + 1];
    }
}

extern "C" void kernel_launch(void* const* d_in, const int* in_sizes, int n_in,
                              void* d_out, int out_size, void* d_ws, size_t ws_size,
                              hipStream_t stream) {
    const float* x    = (const float*)d_in[0];
    const int* eidx   = (const int*)d_in[1];
    const int* esrc   = eidx;
    const int* edst   = eidx + NE;
    const int* edelta = (const int*)d_in[2];
    const int* eself  = (const int*)d_in[3];
    const float* w0a  = (const float*)d_in[5];
    const float* b0a  = (const float*)d_in[6];
    const float* w0v  = (const float*)d_in[7];
    const float* b0v  = (const float*)d_in[8];
    const float* bn0  = (const float*)d_in[9];
    const float* bnn  = (const float*)d_in[10];
    const float* ecb1 = (const float*)d_in[11];
    const float* ecf1 = (const float*)d_in[12];
    const float* ecb2 = (const float*)d_in[13];
    const float* ecf2 = (const float*)d_in[14];
    const float* wh   = (const float*)d_in[15];
    const float* bh   = (const float*)d_in[16];
    float* out = (float*)d_out;

    char* wsb = (char*)d_ws;
    size_t off = 0;
    auto take = [&](size_t bytes) -> char* {
        char* p = wsb + off;
        off = (off + bytes + 255) & ~(size_t)255;
        return p;
    };
    bf16_t* W16  = (bf16_t*)take(589824 * 2);
    float*  SBN  = (float*)take(28 * 256 * 4);
    int*    cnts = (int*)take(256);
    int*    lst1 = (int*)take((size_t)NE * 4);
    int*    lst2 = (int*)take((size_t)NE * 4);
    float*  U    = (float*)take((size_t)NPAD * C * 4);
    u32*    agg  = (u32*)take((size_t)NPAD * C * 4);
    float*  G0   = (float*)take((size_t)NPAD * C * 4);
    float*  G1   = (float*)take((size_t)NPAD * C * 4);
    float*  G2   = (float*)take((size_t)NPAD * C * 4);
    bf16_t* H    = (bf16_t*)take((size_t)EPAD * C * 2);
    (void)ws_size; (void)in_sizes; (void)n_in; (void)out_size;

    bf16_t* w0a_b = W16;
    bf16_t* w0v_b = W16 + 131072;
    bf16_t* fc1_b = W16 + 196608;   // [8][128][256]
    bf16_t* fc2_b = W16 + 458752;   // [8][128][128]

    hipMemsetAsync(cnts, 0, 8, stream);
    hipMemsetAsync(agg, 0, (size_t)NNODE * C * 4, stream);
    compact_kernel<<<(NE + 255) / 256, 256, 0, stream>>>(edelta, eself, lst1, lst2, cnts);
    cvt_weights<<<1024, 256, 0, stream>>>(w0a, w0v, ecf1, ecf2, W16);
    prep_bn<<<14, 256, 0, stream>>>(bn0, bnn, ecb1, ecb2, SBN);

    // ---- layer 0 ----
    {
        GArgs ga{};
        ga.A = x; ga.lda = 2048; ga.B = w0a_b; ga.ldb = IN_A; ga.K = IN_A;
        ga.M = NA; ga.cnt = nullptr; ga.sA = nullptr; ga.shA = nullptr;
        ga.sE = SBN; ga.shE = SBN + 128; ga.bias = b0a; ga.outF = G0;
        gemm_kernel<1, 1><<<APAD / 64, 256, 0, stream>>>(ga);
        GArgs gv{};
        gv.A = x + (size_t)NA * 2048 + 1024; gv.lda = 2048; gv.B = w0v_b; gv.ldb = IN_V; gv.K = IN_V;
        gv.M = NV; gv.cnt = nullptr; gv.sA = nullptr; gv.shA = nullptr;
        gv.sE = SBN; gv.shE = SBN + 128; gv.bias = b0v; gv.outF = G0 + (size_t)NA * C;
        gemm_kernel<1, 1><<<APAD / 64, 256, 0, stream>>>(gv);
    }
    head_kernel<<<NNODE / 4, 256, 0, stream>>>(G0, wh, bh, out, 1);

    // ---- 4 pairs of EdgeConv ----
    float* G[3] = { G0, G1, G2 };
    int cur = 0;
    for (int p = 0; p < 4; p++) {
        int mid = (cur + 1) % 3, nxt = (cur + 2) % 3;
        for (int half = 0; half < 2; half++) {
            int k = p * 2 + half;
            const float* fin = G[half ? mid : cur];
            const int* lst = (half == 0) ? lst1 : lst2;
            const int* cp = cnts + half;
            // K1: U = relu(bn1a(fin)) @ W1a^T
            GArgs k1{};
            k1.A = fin; k1.lda = C; k1.B = fc1_b + (size_t)k * 32768; k1.ldb = 256; k1.K = C;
            k1.M = NNODE; k1.cnt = nullptr;
            k1.sA = SBN + (4 + k) * 256; k1.shA = k1.sA + 128; k1.outF = U;
            gemm_kernel<1, 0><<<NPAD / 64, 256, 0, stream>>>(k1);
            // K3: H = bf16(relu(bn2( relu(bn1b(F[src]-F[dst])) @ W1b^T + U[dst] )))
            GArgs k3{};
            k3.F = fin; k3.elist = lst; k3.esrc = esrc; k3.edst = edst;
            k3.cnt = cp; k3.M = NE;
            k3.sA = SBN + (12 + k) * 256; k3.shA = k3.sA + 128;
            k3.B = fc1_b + (size_t)k * 32768 + 128; k3.ldb = 256; k3.K = C;
            k3.sE = SBN + (20 + k) * 256; k3.shE = k3.sE + 128;
            k3.Ugat = U; k3.outH = H;
            gemm_kernel<2, 2><<<EPAD / 64, 256, 0, stream>>>(k3);
            // K4: msg = H @ W2^T -> atomicMax scatter into agg[dst]
            GArgs k4{};
            k4.A = H; k4.lda = C; k4.B = fc2_b + (size_t)k * 16384; k4.ldb = C; k4.K = C;
            k4.cnt = cp; k4.M = NE; k4.elist = lst; k4.edst = edst; k4.agg = agg;
            gemm_kernel<0, 3><<<EPAD / 64, 256, 0, stream>>>(k4);
            // K5: decode (+post), re-zero agg
            if (half == 0) {
                decode_kernel<<<2048, 256, 0, stream>>>(agg, nullptr, nullptr, nullptr, G[mid], 0);
            } else {
                int mode = (p == 0) ? 1 : ((p == 3) ? 3 : 2);
                const float* res = (p == 0) ? nullptr : G[cur];
                decode_kernel<<<2048, 256, 0, stream>>>(agg, res, SBN + (1 + p) * 256,
                                                        SBN + (1 + p) * 256 + 128, G[nxt], mode);
            }
        }
        cur = nxt;
    }
    head_kernel<<<NNODE / 4, 256, 0, stream>>>(G[cur], wh, bh, out, 0);
}

// Round 2
// 651.512 us; speedup vs baseline: 1.2159x; 1.2159x over previous
//
#include <hip/hip_runtime.h>

#define C 128
#define IN_A 1024
#define IN_V 512
#define NNODE 20000
#define NE 120000
#define NA 10000
#define NV 10000
#define EPSBN 1e-5f

#define NPAD 20032   // 64-aligned >= NNODE
#define EPAD 120064  // 64-aligned >= NE
#define APAD 10048   // 64-aligned >= NA/NV
#define NSTRIDE 20032

typedef __bf16 bf16_t;
typedef bf16_t bf16x8 __attribute__((ext_vector_type(8)));
typedef float f32x4 __attribute__((ext_vector_type(4)));
typedef unsigned int u32;

__device__ __forceinline__ f32x4 ld4(const float* p) {
    return *reinterpret_cast<const f32x4*>(p);
}

// ---------------- node GEMM (layer0 / K1) ----------------
struct GArgs {
    const float* A; long lda;
    const bf16_t* B; long ldb; int K;
    int M;
    const float* sA; const float* shA;   // bn over K channels (null => raw cvt)
    const float* sE; const float* shE;   // EPI1 bn over out channels
    const float* bias;                   // EPI1
    float* outF;
};

// EPI: 0 = store f32, 1 = bias+bn+relu store f32
template<int EPI>
__global__ __launch_bounds__(256) void node_gemm(GArgs g) {
    int wave = threadIdx.x >> 6;
    int lane = threadIdx.x & 63;
    int m0 = blockIdx.x * 64 + wave * 16;
    if (m0 >= g.M) return;

    int arow = m0 + (lane & 15);
    int ar = arow < g.M ? arow : (g.M - 1);
    int ak = (lane >> 4) << 3;

    const bf16_t* Bp = g.B + (size_t)(lane & 15) * g.ldb + ak;
    const float* Af = g.A + (size_t)ar * g.lda + ak;

    f32x4 acc[8];
#pragma unroll
    for (int i = 0; i < 8; i++) acc[i] = (f32x4)(0.0f);

    for (int kk = 0; kk < g.K; kk += 32) {
        f32x4 v0 = ld4(Af + kk), v1 = ld4(Af + kk + 4);
        if (g.sA) {
            f32x4 s0 = ld4(g.sA + kk + ak), s1 = ld4(g.sA + kk + ak + 4);
            f32x4 h0 = ld4(g.shA + kk + ak), h1 = ld4(g.shA + kk + ak + 4);
#pragma unroll
            for (int j = 0; j < 4; j++) {
                v0[j] = fmaxf(v0[j] * s0[j] + h0[j], 0.0f);
                v1[j] = fmaxf(v1[j] * s1[j] + h1[j], 0.0f);
            }
        }
        bf16x8 a;
#pragma unroll
        for (int j = 0; j < 4; j++) { a[j] = (bf16_t)v0[j]; a[4 + j] = (bf16_t)v1[j]; }
#pragma unroll
        for (int nt = 0; nt < 8; nt++) {
            bf16x8 b = *reinterpret_cast<const bf16x8*>(Bp + (size_t)nt * 16 * g.ldb + kk);
            acc[nt] = __builtin_amdgcn_mfma_f32_16x16x32_bf16(a, b, acc[nt], 0, 0, 0);
        }
    }

    int cb = lane & 15;
    float se[8], he[8], bsv[8];
    if (EPI == 1) {
#pragma unroll
        for (int nt = 0; nt < 8; nt++) {
            se[nt] = g.sE[nt * 16 + cb]; he[nt] = g.shE[nt * 16 + cb];
            bsv[nt] = g.bias[nt * 16 + cb];
        }
    }
#pragma unroll
    for (int j = 0; j < 4; j++) {
        int m = m0 + (lane >> 4) * 4 + j;
        if (m >= g.M) continue;
#pragma unroll
        for (int nt = 0; nt < 8; nt++) {
            int n = nt * 16 + cb;
            float v = acc[nt][j];
            if (EPI == 0) g.outF[(size_t)m * C + n] = v;
            else g.outF[(size_t)m * C + n] = fmaxf((v + bsv[nt]) * se[nt] + he[nt], 0.0f);
        }
    }
}

// ---------------- fused edge kernel: GEMM1 + bn2/relu/U + LDS transpose + GEMM2 ----------------
struct EArgs {
    const float* F;
    const int* psrc; const int* pdst;
    const int* cnt;
    const bf16_t* B1;   // W1b rows, ldb 256
    const bf16_t* B2;   // W2 rows, ldb 128
    const float* sA; const float* shA;   // bn1b
    const float* sE; const float* shE;   // bn2
    const float* U;
    bf16_t* msg;
};

__global__ __launch_bounds__(256) void edge_fused(EArgs g) {
    __shared__ float hlds[4 * 2048];
    int Mreal = *g.cnt;
    int wave = threadIdx.x >> 6;
    int lane = threadIdx.x & 63;
    int m0b = blockIdx.x * 64;
    if (m0b >= Mreal) return;                 // uniform per block
    int m0 = m0b + wave * 16;

    int arow = m0 + (lane & 15);
    int ar = arow < Mreal ? arow : (Mreal - 1);
    int ak = (lane >> 4) << 3;

    const float* Fs = g.F + (size_t)g.psrc[ar] * C + ak;
    const float* Fd = g.F + (size_t)g.pdst[ar] * C + ak;
    const bf16_t* B1p = g.B1 + (size_t)(lane & 15) * 256 + ak;

    f32x4 acc[8];
#pragma unroll
    for (int i = 0; i < 8; i++) acc[i] = (f32x4)(0.0f);

#pragma unroll
    for (int kk = 0; kk < C; kk += 32) {
        f32x4 vs0 = ld4(Fs + kk), vs1 = ld4(Fs + kk + 4);
        f32x4 vd0 = ld4(Fd + kk), vd1 = ld4(Fd + kk + 4);
        f32x4 s0 = ld4(g.sA + kk + ak), s1 = ld4(g.sA + kk + ak + 4);
        f32x4 h0 = ld4(g.shA + kk + ak), h1 = ld4(g.shA + kk + ak + 4);
        bf16x8 a;
#pragma unroll
        for (int j = 0; j < 4; j++) {
            float t0 = fmaxf((vs0[j] - vd0[j]) * s0[j] + h0[j], 0.0f);
            float t1 = fmaxf((vs1[j] - vd1[j]) * s1[j] + h1[j], 0.0f);
            a[j] = (bf16_t)t0; a[4 + j] = (bf16_t)t1;
        }
#pragma unroll
        for (int nt = 0; nt < 8; nt++) {
            bf16x8 b = *reinterpret_cast<const bf16x8*>(B1p + (size_t)nt * 16 * 256 + kk);
            acc[nt] = __builtin_amdgcn_mfma_f32_16x16x32_bf16(a, b, acc[nt], 0, 0, 0);
        }
    }

    // mid-epilogue: +U[dst], bn2, relu -> swizzled LDS (f32)
    int cb = lane & 15;
    float se[8], he[8];
#pragma unroll
    for (int nt = 0; nt < 8; nt++) { se[nt] = g.sE[nt * 16 + cb]; he[nt] = g.shE[nt * 16 + cb]; }
    int rbase = (lane >> 4) * 4;
    float* wl = hlds + wave * 2048;
#pragma unroll
    for (int j = 0; j < 4; j++) {
        int m = m0 + rbase + j;
        int mc = m < Mreal ? m : (Mreal - 1);
        const float* Ur = g.U + (size_t)g.pdst[mc] * C;
        int r = rbase + j;
        int sw = (r & 7) << 2;
#pragma unroll
        for (int nt = 0; nt < 8; nt++) {
            int n = nt * 16 + cb;
            float v = acc[nt][j] + Ur[n];
            wl[(r * 128 + n) ^ sw] = fmaxf(v * se[nt] + he[nt], 0.0f);
        }
    }
    __syncthreads();

    // GEMM2: A = H tile from LDS, B = W2
    const bf16_t* B2p = g.B2 + (size_t)(lane & 15) * C + ak;
#pragma unroll
    for (int i = 0; i < 8; i++) acc[i] = (f32x4)(0.0f);
    int rr = lane & 15;
    int swz = (rr & 7) << 2;
    const float* rl = hlds + wave * 2048;
#pragma unroll
    for (int kk = 0; kk < C; kk += 32) {
        int c0 = kk + ak;
        f32x4 v0 = *reinterpret_cast<const f32x4*>(rl + ((rr * 128 + c0) ^ swz));
        f32x4 v1 = *reinterpret_cast<const f32x4*>(rl + ((rr * 128 + c0 + 4) ^ swz));
        bf16x8 a;
#pragma unroll
        for (int j = 0; j < 4; j++) { a[j] = (bf16_t)v0[j]; a[4 + j] = (bf16_t)v1[j]; }
#pragma unroll
        for (int nt = 0; nt < 8; nt++) {
            bf16x8 b = *reinterpret_cast<const bf16x8*>(B2p + (size_t)nt * 16 * C + kk);
            acc[nt] = __builtin_amdgcn_mfma_f32_16x16x32_bf16(a, b, acc[nt], 0, 0, 0);
        }
    }
#pragma unroll
    for (int j = 0; j < 4; j++) {
        int m = m0 + rbase + j;
        if (m >= Mreal) continue;
        bf16_t* op = g.msg + (size_t)m * C;
#pragma unroll
        for (int nt = 0; nt < 8; nt++) op[nt * 16 + cb] = (bf16_t)acc[nt][j];
    }
}

// ---------------- prep: cvt weights + bn fold + indegree count ----------------
__global__ void prep0(const float* __restrict__ w0a, const float* __restrict__ w0v,
                      const float* __restrict__ fc1, const float* __restrict__ fc2,
                      const float* __restrict__ bn0, const float* __restrict__ bnn,
                      const float* __restrict__ ecb1, const float* __restrict__ ecb2,
                      const int* __restrict__ edelta, const int* __restrict__ eself,
                      const int* __restrict__ edst,
                      bf16_t* __restrict__ W16, float* __restrict__ SBN, int* __restrict__ indeg) {
    int b = blockIdx.x, t = threadIdx.x;
    if (b < 2304) {
        int i = b * 256 + t;   // < 589824 exactly
        float v;
        if (i < 131072) v = w0a[i];
        else if (i < 196608) v = w0v[i - 131072];
        else if (i < 458752) v = fc1[i - 196608];
        else v = fc2[i - 458752];
        W16[i] = (bf16_t)v;
    } else if (b < 2318) {
        int i = (b - 2304) * 256 + t;
        if (i >= 28 * 128) return;
        int pair = i >> 7, c = i & 127;
        float gg, bb, mm, vv;
        if (pair == 0)      { gg = bn0[c]; bb = bn0[128 + c]; mm = bn0[256 + c]; vv = bn0[384 + c]; }
        else if (pair < 4)  { const float* q = bnn + (pair - 1) * 512;
                              gg = q[c]; bb = q[128 + c]; mm = q[256 + c]; vv = q[384 + c]; }
        else if (pair < 12) { const float* q = ecb1 + (pair - 4) * 1024;
                              gg = q[c]; bb = q[256 + c]; mm = q[512 + c]; vv = q[768 + c]; }
        else if (pair < 20) { const float* q = ecb1 + (pair - 12) * 1024 + 128;
                              gg = q[c]; bb = q[256 + c]; mm = q[512 + c]; vv = q[768 + c]; }
        else                { const float* q = ecb2 + (pair - 20) * 512;
                              gg = q[c]; bb = q[128 + c]; mm = q[256 + c]; vv = q[384 + c]; }
        float s = gg * rsqrtf(vv + EPSBN);
        SBN[pair * 256 + c] = s;
        SBN[pair * 256 + 128 + c] = bb - mm * s;
    } else {
        int e = (b - 2318) * 256 + t;
        if (e >= NE) return;
        int d = edelta[e];
        int dn = edst[e];
        if (d < 1) atomicAdd(indeg + dn, 1);
        if (((d >= 1) && (d < 4)) || (eself[e] == 1)) atomicAdd(indeg + NSTRIDE + dn, 1);
    }
}

// ---------------- exclusive scan over indegrees (one block per half) ----------------
__global__ __launch_bounds__(1024) void scan_kernel(const int* __restrict__ indeg,
                                                    int* __restrict__ rowstart,
                                                    int* __restrict__ cursor,
                                                    int* __restrict__ cnts) {
    __shared__ int sh[1024];
    int half = blockIdx.x;
    const int* in = indeg + half * NSTRIDE;
    int* rs = rowstart + half * NSTRIDE;
    int* cu = cursor + half * NSTRIDE;
    int t = threadIdx.x;
    int base = t * 20;
    int s = 0;
    for (int i = 0; i < 20; i++) { int idx = base + i; if (idx < NNODE) s += in[idx]; }
    sh[t] = s;
    __syncthreads();
    for (int off = 1; off < 1024; off <<= 1) {
        int v = (t >= off) ? sh[t - off] : 0;
        __syncthreads();
        sh[t] += v;
        __syncthreads();
    }
    int run = sh[t] - s;
    for (int i = 0; i < 20; i++) {
        int idx = base + i;
        if (idx < NNODE) { int v = in[idx]; rs[idx] = run; cu[idx] = run; run += v; }
    }
    if (t == 1023) { rs[NNODE] = sh[1023]; cnts[half] = sh[1023]; }
}

// ---------------- scatter edges into CSR position arrays ----------------
__global__ void scatter_kernel(const int* __restrict__ edelta, const int* __restrict__ eself,
                               const int* __restrict__ esrc, const int* __restrict__ edst,
                               int* __restrict__ cursor, int* __restrict__ psrc, int* __restrict__ pdst) {
    int e = blockIdx.x * 256 + threadIdx.x;
    if (e >= NE) return;
    int d = edelta[e];
    int dn = edst[e], sn = esrc[e];
    if (d < 1) {
        int p = atomicAdd(cursor + dn, 1);
        psrc[p] = sn; pdst[p] = dn;
    }
    if (((d >= 1) && (d < 4)) || (eself[e] == 1)) {
        int p = atomicAdd(cursor + NSTRIDE + dn, 1);
        psrc[EPAD + p] = sn; pdst[EPAD + p] = dn;
    }
}

// ---------------- gather max-aggregation + post ops ----------------
// mode: 0 plain store; 1 bn+relu; 2 res+bn+relu; 4 res + final head -> outHead
struct AArgs {
    const bf16_t* msg; const int* rowstart;
    const float* res; const float* s; const float* sh;
    float* outG;
    const float* wh; const float* bh; float* outHead;
    int mode;
};
__global__ __launch_bounds__(256) void agg_kernel(AArgs a) {
    int node = blockIdx.x * 4 + (threadIdx.x >> 6);
    int lane = threadIdx.x & 63;
    if (node >= NNODE) return;
    int p0 = a.rowstart[node], p1 = a.rowstart[node + 1];
    float v0 = -INFINITY, v1 = -INFINITY;
    const u32* mp = (const u32*)a.msg + lane;
    for (int p = p0; p < p1; ++p) {
        u32 u = mp[(size_t)p * 64];
        v0 = fmaxf(v0, __uint_as_float(u << 16));
        v1 = fmaxf(v1, __uint_as_float(u & 0xffff0000u));
    }
    if (p1 == p0) { v0 = 0.0f; v1 = 0.0f; }
    int c = lane * 2;
    if (a.mode >= 2) { v0 += a.res[(size_t)node * C + c]; v1 += a.res[(size_t)node * C + c + 1]; }
    if (a.mode == 1 || a.mode == 2) {
        v0 = fmaxf(v0 * a.s[c] + a.sh[c], 0.0f);
        v1 = fmaxf(v1 * a.s[c + 1] + a.sh[c + 1], 0.0f);
    }
    if (a.mode == 4) {
        float q0 = v0 * a.wh[c] + v1 * a.wh[c + 1];
        float q1 = v0 * a.wh[128 + c] + v1 * a.wh[128 + c + 1];
#pragma unroll
        for (int off = 32; off; off >>= 1) { q0 += __shfl_down(q0, off); q1 += __shfl_down(q1, off); }
        if (lane == 0) {
            a.outHead[(size_t)node * 2 + 0] = q0 + a.bh[0];
            a.outHead[(size_t)node * 2 + 1] = q1 + a.bh[1];
        }
        return;
    }
    float2 w; w.x = v0; w.y = v1;
    *((float2*)(a.outG + (size_t)node * C) + lane) = w;
}

// ---------------- audio/video heads from g0 ----------------
__global__ void head_av(const float* __restrict__ F, const float* __restrict__ wh,
                        const float* __restrict__ bh, float* __restrict__ out) {
    int node = blockIdx.x * 4 + (threadIdx.x >> 6);
    int lane = threadIdx.x & 63;
    if (node >= NNODE) return;
    int hsel = (node < NA) ? 1 : 2;
    const float* w = wh + hsel * 256;
    const float* f = F + (size_t)node * C;
    float f0 = f[lane], f1 = f[lane + 64];
    float p0 = f0 * w[lane] + f1 * w[lane + 64];
    float p1 = f0 * w[128 + lane] + f1 * w[192 + lane];
#pragma unroll
    for (int o = 32; o; o >>= 1) { p0 += __shfl_down(p0, o); p1 += __shfl_down(p1, o); }
    if (lane == 0) {
        float* op = (node < NA) ? (out + 40000 + (size_t)node * 2)
                                : (out + 60000 + (size_t)(node - NA) * 2);
        op[0] = p0 + bh[hsel * 2 + 0];
        op[1] = p1 + bh[hsel * 2 + 1];
    }
}

extern "C" void kernel_launch(void* const* d_in, const int* in_sizes, int n_in,
                              void* d_out, int out_size, void* d_ws, size_t ws_size,
                              hipStream_t stream) {
    const float* x    = (const float*)d_in[0];
    const int* eidx   = (const int*)d_in[1];
    const int* esrc   = eidx;
    const int* edst   = eidx + NE;
    const int* edelta = (const int*)d_in[2];
    const int* eself  = (const int*)d_in[3];
    const float* w0a  = (const float*)d_in[5];
    const float* b0a  = (const float*)d_in[6];
    const float* w0v  = (const float*)d_in[7];
    const float* b0v  = (const float*)d_in[8];
    const float* bn0  = (const float*)d_in[9];
    const float* bnn  = (const float*)d_in[10];
    const float* ecb1 = (const float*)d_in[11];
    const float* ecf1 = (const float*)d_in[12];
    const float* ecb2 = (const float*)d_in[13];
    const float* ecf2 = (const float*)d_in[14];
    const float* wh   = (const float*)d_in[15];
    const float* bh   = (const float*)d_in[16];
    float* out = (float*)d_out;

    char* wsb = (char*)d_ws;
    size_t off = 0;
    auto take = [&](size_t bytes) -> char* {
        char* p = wsb + off;
        off = (off + bytes + 255) & ~(size_t)255;
        return p;
    };
    bf16_t* W16   = (bf16_t*)take(589824 * 2);
    float*  SBN   = (float*)take(28 * 256 * 4);
    int*    cnts  = (int*)take(256);
    int*    indeg = (int*)take(2 * NSTRIDE * 4);
    int*    rowst = (int*)take(2 * NSTRIDE * 4);
    int*    curs  = (int*)take(2 * NSTRIDE * 4);
    int*    psrc  = (int*)take(2 * (size_t)EPAD * 4);
    int*    pdst  = (int*)take(2 * (size_t)EPAD * 4);
    float*  U     = (float*)take((size_t)NPAD * C * 4);
    float*  G0    = (float*)take((size_t)NPAD * C * 4);
    float*  G1    = (float*)take((size_t)NPAD * C * 4);
    float*  G2    = (float*)take((size_t)NPAD * C * 4);
    bf16_t* msg   = (bf16_t*)take((size_t)EPAD * C * 2);
    (void)ws_size; (void)in_sizes; (void)n_in; (void)out_size;

    bf16_t* w0a_b = W16;
    bf16_t* w0v_b = W16 + 131072;
    bf16_t* fc1_b = W16 + 196608;   // [8][128][256]
    bf16_t* fc2_b = W16 + 458752;   // [8][128][128]

    hipMemsetAsync(indeg, 0, 2 * NSTRIDE * 4, stream);
    prep0<<<2787, 256, 0, stream>>>(w0a, w0v, ecf1, ecf2, bn0, bnn, ecb1, ecb2,
                                    edelta, eself, edst, W16, SBN, indeg);
    scan_kernel<<<2, 1024, 0, stream>>>(indeg, rowst, curs, cnts);
    scatter_kernel<<<(NE + 255) / 256, 256, 0, stream>>>(edelta, eself, esrc, edst, curs, psrc, pdst);

    // ---- layer 0 ----
    {
        GArgs ga{};
        ga.A = x; ga.lda = 2048; ga.B = w0a_b; ga.ldb = IN_A; ga.K = IN_A;
        ga.M = NA; ga.sA = nullptr; ga.shA = nullptr;
        ga.sE = SBN; ga.shE = SBN + 128; ga.bias = b0a; ga.outF = G0;
        node_gemm<1><<<APAD / 64, 256, 0, stream>>>(ga);
        GArgs gv{};
        gv.A = x + (size_t)NA * 2048 + 1024; gv.lda = 2048; gv.B = w0v_b; gv.ldb = IN_V; gv.K = IN_V;
        gv.M = NV; gv.sA = nullptr; gv.shA = nullptr;
        gv.sE = SBN; gv.shE = SBN + 128; gv.bias = b0v; gv.outF = G0 + (size_t)NA * C;
        node_gemm<1><<<APAD / 64, 256, 0, stream>>>(gv);
    }
    head_av<<<NNODE / 4, 256, 0, stream>>>(G0, wh, bh, out);

    // ---- 4 pairs of EdgeConv ----
    float* G[3] = { G0, G1, G2 };
    int cur = 0;
    for (int p = 0; p < 4; p++) {
        int mid = (cur + 1) % 3, nxt = (cur + 2) % 3;
        for (int half = 0; half < 2; half++) {
            int k = p * 2 + half;
            const float* fin = G[half ? mid : cur];
            // K1: U = relu(bn1a(fin)) @ W1a^T
            GArgs k1{};
            k1.A = fin; k1.lda = C; k1.B = fc1_b + (size_t)k * 32768; k1.ldb = 256; k1.K = C;
            k1.M = NNODE;
            k1.sA = SBN + (4 + k) * 256; k1.shA = k1.sA + 128; k1.outF = U;
            node_gemm<0><<<NPAD / 64, 256, 0, stream>>>(k1);
            // fused edge kernel
            EArgs ke{};
            ke.F = fin; ke.psrc = psrc + (size_t)half * EPAD; ke.pdst = pdst + (size_t)half * EPAD;
            ke.cnt = cnts + half;
            ke.B1 = fc1_b + (size_t)k * 32768 + 128;
            ke.B2 = fc2_b + (size_t)k * 16384;
            ke.sA = SBN + (12 + k) * 256; ke.shA = ke.sA + 128;
            ke.sE = SBN + (20 + k) * 256; ke.shE = ke.sE + 128;
            ke.U = U; ke.msg = msg;
            edge_fused<<<EPAD / 64, 256, 0, stream>>>(ke);
            // aggregation + post
            AArgs aa{};
            aa.msg = msg; aa.rowstart = rowst + (size_t)half * NSTRIDE;
            if (half == 0) {
                aa.mode = 0; aa.outG = G[mid];
            } else {
                if (p == 0) { aa.mode = 1; }
                else if (p == 3) { aa.mode = 4; aa.res = G[cur]; aa.wh = wh; aa.bh = bh; aa.outHead = out; }
                else { aa.mode = 2; aa.res = G[cur]; }
                aa.s = SBN + (1 + p) * 256; aa.sh = SBN + (1 + p) * 256 + 128;
                aa.outG = G[nxt];
            }
            agg_kernel<<<NNODE / 4, 256, 0, stream>>>(aa);
        }
        cur = nxt;
    }
}